// Round 1
// baseline (32.309 us; speedup 1.0000x reference)
//
#include <hip/hip_runtime.h>

// Problem constants (fixed by the reference).
#define BSZ    16      // batch
#define NN     1024    // tokens per batch
#define DIN    512     // input dim
#define KD     256     // NUM_CAPS * DIM_CAPS
#define NCAPS  16
#define EPS    1e-7f

#define ROWS_PER_BLK 32
#define NCHUNK (NN / ROWS_PER_BLK)   // 32 chunks per batch
#define NPART  (NCHUNK * 2)          // 64 partial rows per batch (2 parities)

// Kernel A: deterministic partial column sums of inputs over n.
// grid = BSZ*NCHUNK = 512 blocks, 256 threads.
// Thread t: parity = t>>7 (even/odd rows), col4 = t&127 (float4 column).
// Each block covers 32 rows x 512 cols; per iteration the block reads two
// full rows (4 KB contiguous) — fully coalesced 16 B/lane.
// P[(blk*2 + parity)][i] = sum over its 16 rows of inputs[b][n][i].
__global__ __launch_bounds__(256) void colsum_partial(
    const float* __restrict__ in, float* __restrict__ P)
{
    int blk = blockIdx.x;
    int b   = blk / NCHUNK;
    int c   = blk % NCHUNK;
    int t   = threadIdx.x;
    int par  = t >> 7;      // 0 or 1
    int col4 = t & 127;     // float4 column index

    const float4* base = (const float4*)in
        + (size_t)(b * NN + c * ROWS_PER_BLK) * (DIN / 4);

    float4 acc = make_float4(0.f, 0.f, 0.f, 0.f);
    #pragma unroll
    for (int r = 0; r < ROWS_PER_BLK / 2; ++r) {
        float4 v = base[(size_t)(2 * r + par) * (DIN / 4) + col4];
        acc.x += v.x; acc.y += v.y; acc.z += v.z; acc.w += v.w;
    }
    float4* Pout = (float4*)P + (size_t)(blk * 2 + par) * (DIN / 4) + col4;
    *Pout = acc;
}

// Kernel B: one block per batch b (256 threads).
// 1) xs[i] = sum over 64 partial rows of P  (i = 0..511, staged in LDS)
// 2) H[d]  = sum_i xs[i] * W[i*KD + d]  (thread t owns d = t; W coalesced)
// 3) s = H/16; block-reduce sq = sum_d s^2; squash; write 16 k-copies.
__global__ __launch_bounds__(256) void routing_out(
    const float* __restrict__ P, const float* __restrict__ W,
    float* __restrict__ out)
{
    __shared__ float xs[DIN];
    __shared__ float red[256];
    int b = blockIdx.x;
    int t = threadIdx.x;

    // Reduce partials (deterministic fixed order).
    for (int i = t; i < DIN; i += 256) {
        const float* p = P + (size_t)b * NPART * DIN + i;
        float a = 0.f;
        #pragma unroll
        for (int j = 0; j < NPART; ++j) a += p[(size_t)j * DIN];
        xs[i] = a;
    }
    __syncthreads();

    // Tiny GEMM: thread t computes output dim d = t.
    // xs[i] is a broadcast LDS read (no bank conflict); W read coalesced.
    float acc = 0.f;
    #pragma unroll 8
    for (int i = 0; i < DIN; ++i) acc += xs[i] * W[i * KD + t];
    float s = acc * (1.0f / 16.0f);

    // Block reduction of sum of squares over the 256 dims.
    red[t] = s * s;
    __syncthreads();
    for (int off = 128; off > 0; off >>= 1) {
        if (t < off) red[t] += red[t + off];
        __syncthreads();
    }
    float sq = red[0];

    // squash: (sq/(1+sq)) * s / sqrt(sq + eps)
    float scale = (sq / (1.0f + sq)) / sqrtf(sq + EPS);
    float o = scale * s;

    // Output is identical for all k capsules (exact routing degeneracy).
    #pragma unroll
    for (int k = 0; k < NCAPS; ++k)
        out[((size_t)b * NCAPS + k) * KD + t] = o;
}

extern "C" void kernel_launch(void* const* d_in, const int* in_sizes, int n_in,
                              void* d_out, int out_size, void* d_ws, size_t ws_size,
                              hipStream_t stream)
{
    const float* in = (const float*)d_in[0];  // [16,1024,512] f32
    const float* W  = (const float*)d_in[1];  // [512,256] f32
    float* out = (float*)d_out;               // [16,16,256] f32
    float* P   = (float*)d_ws;                // needs 16*64*512*4 = 2 MB scratch

    colsum_partial<<<BSZ * NCHUNK, 256, 0, stream>>>(in, P);
    routing_out<<<BSZ, 256, 0, stream>>>(P, W, out);
}

// Round 2
// 15.388 us; speedup vs baseline: 2.0997x; 2.0997x over previous
//
#include <hip/hip_runtime.h>

// Problem constants (fixed by the reference).
#define BSZ    16      // batch
#define NN     1024    // tokens per batch
#define DIN    512     // input dim
#define KD     256     // NUM_CAPS * DIM_CAPS
#define NCAPS  16
#define EPS    1e-7f

#define ROWS_PER_BLK 32
#define NCHUNK (NN / ROWS_PER_BLK)   // 32 partial rows per batch
#define NSPLIT 16                    // i-dimension splits for the tiny GEMM
#define ICHUNK (DIN / NSPLIT)        // 32

// ---------------------------------------------------------------------------
// Kernel A: partial column sums of inputs over n, one output row per block.
// grid = 512 blocks (batch-major: blk = b*NCHUNK + c), 256 threads.
// Thread t: parity = t>>7 (even/odd rows), col4 = t&127 (float4 column).
// Per iteration the block reads two full 2 KB rows — coalesced 16 B/lane.
// Parity pair is reduced through LDS so each block emits ONE row:
//   P[blk][i] = sum over its 32 rows of inputs[.][n][i].   (P: 512x512 f32)
// ---------------------------------------------------------------------------
__global__ __launch_bounds__(256) void colsum_partial(
    const float* __restrict__ in, float* __restrict__ P)
{
    __shared__ float4 sh[128];
    int blk = blockIdx.x;
    int t   = threadIdx.x;
    int par  = t >> 7;      // 0 or 1
    int col4 = t & 127;     // float4 column index

    const float4* base = (const float4*)in
        + (size_t)blk * ROWS_PER_BLK * (DIN / 4);

    float4 acc = make_float4(0.f, 0.f, 0.f, 0.f);
    #pragma unroll
    for (int r = 0; r < ROWS_PER_BLK / 2; ++r) {
        float4 v = base[(size_t)(2 * r + par) * (DIN / 4) + col4];
        acc.x += v.x; acc.y += v.y; acc.z += v.z; acc.w += v.w;
    }
    if (par) sh[col4] = acc;
    __syncthreads();
    if (!par) {
        float4 o = sh[col4];
        acc.x += o.x; acc.y += o.y; acc.z += o.z; acc.w += o.w;
        ((float4*)P)[(size_t)blk * (DIN / 4) + col4] = acc;
    }
}

// ---------------------------------------------------------------------------
// Kernel B: partial tiny-GEMM, split over the i (DIN) dimension.
// grid = BSZ*NSPLIT = 256 blocks (one per CU), 256 threads.
// Block (b,s) owns i in [s*32, s*32+32):
//   1) reduce P's 32 partial rows over that i-chunk -> xs[32] (LDS, fixed order)
//   2) thread t computes P2[b][s][t] = sum_i xs[i] * W[i0+i][t]
// W chunk per block is 32x256x4 = 32 KB, shared by 16 batches -> L2-resident.
// ---------------------------------------------------------------------------
__global__ __launch_bounds__(256) void partial_gemm(
    const float* __restrict__ P, const float* __restrict__ W,
    float* __restrict__ P2)
{
    __shared__ float part[8][ICHUNK];
    __shared__ float xs[ICHUNK];
    int b = blockIdx.x >> 4;         // / NSPLIT
    int s = blockIdx.x & (NSPLIT - 1);
    int t = threadIdx.x;
    int g  = t >> 5;                 // 0..7
    int il = t & 31;                 // i within chunk
    int i0 = s * ICHUNK;

    // Phase 1: each of 8 groups sums 4 partial rows at column i0+il.
    float a = 0.f;
    #pragma unroll
    for (int jj = 0; jj < 4; ++jj) {
        int j = g * 4 + jj;
        a += P[((size_t)b * NCHUNK + j) * DIN + i0 + il];
    }
    part[g][il] = a;
    __syncthreads();
    if (t < ICHUNK) {
        float v = 0.f;
        #pragma unroll
        for (int g2 = 0; g2 < 8; ++g2) v += part[g2][t];
        xs[t] = v;
    }
    __syncthreads();

    // Phase 2: 32-deep dot; xs is an LDS broadcast, W coalesced across t.
    float acc = 0.f;
    #pragma unroll
    for (int i = 0; i < ICHUNK; ++i)
        acc += xs[i] * W[(size_t)(i0 + i) * KD + t];
    P2[((size_t)b * NSPLIT + s) * KD + t] = acc;
}

// ---------------------------------------------------------------------------
// Kernel C: reduce the NSPLIT partials, squash, write 16 identical k-copies.
// grid = BSZ = 16 blocks, 256 threads (thread t owns output dim d = t).
// ---------------------------------------------------------------------------
__global__ __launch_bounds__(256) void squash_out(
    const float* __restrict__ P2, float* __restrict__ out)
{
    __shared__ float red[256];
    int b = blockIdx.x;
    int t = threadIdx.x;

    float acc = 0.f;
    #pragma unroll
    for (int s = 0; s < NSPLIT; ++s)
        acc += P2[((size_t)b * NSPLIT + s) * KD + t];
    float sv = acc * (1.0f / 16.0f);   // softmax c = 1/16 exactly (degeneracy)

    red[t] = sv * sv;
    __syncthreads();
    for (int off = 128; off > 0; off >>= 1) {
        if (t < off) red[t] += red[t + off];
        __syncthreads();
    }
    float sq = red[0];

    float scale = (sq / (1.0f + sq)) / sqrtf(sq + EPS);
    float o = scale * sv;

    #pragma unroll
    for (int k = 0; k < NCAPS; ++k)
        out[((size_t)b * NCAPS + k) * KD + t] = o;
}

extern "C" void kernel_launch(void* const* d_in, const int* in_sizes, int n_in,
                              void* d_out, int out_size, void* d_ws, size_t ws_size,
                              hipStream_t stream)
{
    const float* in = (const float*)d_in[0];  // [16,1024,512] f32
    const float* W  = (const float*)d_in[1];  // [512,256] f32
    float* out = (float*)d_out;               // [16,16,256] f32

    float* P  = (float*)d_ws;                 // 512*512 f32  = 1 MB
    float* P2 = P + (size_t)BSZ * NCHUNK * DIN; // 16*16*256 f32 = 256 KB

    colsum_partial<<<BSZ * NCHUNK, 256, 0, stream>>>(in, P);
    partial_gemm<<<BSZ * NSPLIT, 256, 0, stream>>>(P, W, P2);
    squash_out<<<BSZ, 256, 0, stream>>>(P2, out);
}